// Round 5
// baseline (1067.733 us; speedup 1.0000x reference)
//
#include <hip/hip_runtime.h>
#include <hip/hip_bf16.h>

#define NN 4096
#define NITER 4
#define NSWEEP 5
#define MCS 68     // mailbox/Wc column stride (floats); [64] holds the column's squared norm

// workspace float layout (double-buffered CG vectors INCLUDING y)
#define OFF_STS  64
#define OFF_QRHO (OFF_STS + NN)
#define OFF_DINV (OFF_QRHO + NN)
#define OFF_Y0   (OFF_DINV + NN)
#define OFF_Y1   (OFF_Y0 + NN)
#define OFF_X0   (OFF_Y1 + NN)
#define OFF_X1   (OFF_X0 + NN)
#define OFF_R0   (OFF_X1 + NN)
#define OFF_R1   (OFF_R0 + NN)
#define OFF_P0   (OFF_R1 + NN)
#define OFF_P1   (OFF_P0 + NN)
// per-block pTy partials, double-buffered by iteration parity
#define OFF_PTY0 (OFF_P1 + NN)
#define OFF_PTY1 (OFF_PTY0 + 1024)
// grid-barrier counters: 3 phases x 32-dword (128B) spacing, zeroed per replay
#define OFF_CTR  (OFF_PTY1 + 1024)
#define DH_OFF_BYTES 196608
#define WS_NEED_BF16 (DH_OFF_BYTES + (size_t)NN * NN * 2)
#define GRID_CG 1024

typedef unsigned int uint;
__device__ inline float lo2f(uint w){ return __uint_as_float(w << 16); }
__device__ inline float hi2f(uint w){ return __uint_as_float(w & 0xffff0000u); }
__device__ inline uint f2b(float f){
    uint u = __float_as_uint(f);
    return (u + 0x7FFFu + ((u >> 16) & 1u)) >> 16;   // RNE
}
// 16-lane sum via DPP only (VALU latency, no DS pipe). Valid when the 16 lanes
// of a group are an aligned 16-lane DPP row (group g = lanes 16g..16g+15).
__device__ inline float rsum16(float x){
    int a = __builtin_amdgcn_update_dpp(0, __float_as_int(x), 0xB1, 0xF, 0xF, true);
    float s = x + __int_as_float(a);
    int b = __builtin_amdgcn_update_dpp(0, __float_as_int(s), 0x4E, 0xF, 0xF, true);
    s = s + __int_as_float(b);
    int c = __builtin_amdgcn_update_dpp(0, __float_as_int(s), 0x141, 0xF, 0xF, true);  // row_half_mirror
    s = s + __int_as_float(c);
    int d = __builtin_amdgcn_update_dpp(0, __float_as_int(s), 0x140, 0xF, 0xF, true);  // row_mirror
    s = s + __int_as_float(d);
    return s;
}

// ---- in-kernel grid barrier (monotonic counter per phase; never reused) ----
// Payload correctness: every thread fences (release), block arrives once,
// t0 spins on device-scope acquire load, block releases, fence (acquire side
// cache invalidate). Bounded spin: a residency failure yields wrong results
// instead of a hung container.
__device__ inline void gridbar(uint* c){
    __threadfence();
    __syncthreads();
    if(threadIdx.x == 0){
        __hip_atomic_fetch_add(c, 1u, __ATOMIC_ACQ_REL, __HIP_MEMORY_SCOPE_AGENT);
        long guard = 0;
        while(__hip_atomic_load(c, __ATOMIC_ACQUIRE, __HIP_MEMORY_SCOPE_AGENT) < (uint)GRID_CG){
            __builtin_amdgcn_s_sleep(1);
            if(++guard > 100000000L) break;   // fail loud, not hung
        }
    }
    __syncthreads();
    __threadfence();
}

// ---------------- prep (FALLBACK PATH ONLY): StS + b + approx diag + CG init ----------------
__global__ void k_prep(const float* __restrict__ inp, const float* __restrict__ L,
                       const int*  __restrict__ mask, const float* __restrict__ thP,
                       const float* __restrict__ S,
                       const float* __restrict__ l2p, const float* __restrict__ rhop,
                       float* __restrict__ wf){
    int t = blockIdx.x * 256 + threadIdx.x;   // 4096 threads
    int r = t >> 6, c = t & 63;
    float acc = 0.f, acc2 = 0.f;
    for(int h = 0; h < 64; ++h){
        float sr = S[h*64 + r];
        float sc = S[h*64 + c];
        acc  += sr * sc;
        acc2 += sc * sc;
    }
    wf[OFF_STS + t] = acc;
    float rho = rhop[0], l2 = l2p[0];
    float q = (mask[t] != 0) ? 1.f : 0.f;
    float bi = rho * (L[t] - thP[t]) + q * inp[t];
    float dinv = 1.f / (q + rho + l2 * acc2);   // preconditioner only
    wf[OFF_QRHO + t] = q + rho;
    wf[OFF_DINV + t] = dinv;
    wf[OFF_X0 + t]   = 0.f;
    wf[OFF_R0 + t]   = bi;
    wf[OFF_P0 + t]   = bi * dinv;
}

// ---------------- per-block redundant CG scalar update (no fences needed) ----------------
// pTy of the previous iteration arrives as 1024 per-block partials; its sum is
// folded into the first shuffle-reduction tree (red[0..3]=rz, red[4..7]=pTy).
__device__ inline void cg_prologue(float* __restrict__ wf,
                                   const float* __restrict__ rold, const float* __restrict__ pold,
                                   const float* __restrict__ xold, const float* __restrict__ yold,
                                   float* __restrict__ rnew, float* __restrict__ pnew,
                                   float* __restrict__ xnew,
                                   const float* __restrict__ pty_read,
                                   float* __restrict__ psh,
                                   float* __restrict__ red){
    int tid = threadIdx.x;
    const float* dinv = wf + OFF_DINV;
    float4 r4[4], d4[4];
    float part = 0.f;
    #pragma unroll
    for(int k = 0; k < 4; ++k){
        r4[k] = ((const float4*)rold)[tid + k*256];
        d4[k] = ((const float4*)dinv)[tid + k*256];
        part += r4[k].x*r4[k].x*d4[k].x + r4[k].y*r4[k].y*d4[k].y
              + r4[k].z*r4[k].z*d4[k].z + r4[k].w*r4[k].w*d4[k].w;
    }
    float pp = pty_read[tid] + pty_read[tid+256] + pty_read[tid+512] + pty_read[tid+768];
    for(int m = 32; m >= 1; m >>= 1){
        part += __shfl_xor(part, m, 64);
        pp   += __shfl_xor(pp, m, 64);
    }
    int wave = tid >> 6, lane = tid & 63;
    if(lane == 0){ red[wave] = part; red[4+wave] = pp; }
    __syncthreads();
    float rzold = red[0] + red[1] + red[2] + red[3];
    float ptys  = red[4] + red[5] + red[6] + red[7];
    float alpha = rzold / ptys;
    float4 rn[4], zn[4];
    float part2 = 0.f;
    #pragma unroll
    for(int k = 0; k < 4; ++k){
        float4 y4 = ((const float4*)yold)[tid + k*256];
        rn[k].x = r4[k].x - alpha*y4.x;  rn[k].y = r4[k].y - alpha*y4.y;
        rn[k].z = r4[k].z - alpha*y4.z;  rn[k].w = r4[k].w - alpha*y4.w;
        zn[k].x = rn[k].x*d4[k].x;  zn[k].y = rn[k].y*d4[k].y;
        zn[k].z = rn[k].z*d4[k].z;  zn[k].w = rn[k].w*d4[k].w;
        part2 += rn[k].x*zn[k].x + rn[k].y*zn[k].y + rn[k].z*zn[k].z + rn[k].w*zn[k].w;
    }
    for(int m = 32; m >= 1; m >>= 1) part2 += __shfl_xor(part2, m, 64);
    __syncthreads();                      // all reads of red done
    if(lane == 0) red[wave] = part2;
    __syncthreads();
    float rznew = red[0] + red[1] + red[2] + red[3];
    float beta = rznew / rzold;
    bool b0 = (blockIdx.x == 0);
    #pragma unroll
    for(int k = 0; k < 4; ++k){
        float4 po = ((const float4*)pold)[tid + k*256];
        float4 pn;
        pn.x = zn[k].x + beta*po.x;  pn.y = zn[k].y + beta*po.y;
        pn.z = zn[k].z + beta*po.z;  pn.w = zn[k].w + beta*po.w;
        ((float4*)psh)[tid + k*256] = pn;
        if(b0){
            ((float4*)pnew)[tid + k*256] = pn;
            ((float4*)rnew)[tid + k*256] = rn[k];
            float4 xo = ((const float4*)xold)[tid + k*256];
            float4 xn;
            xn.x = xo.x + alpha*po.x;  xn.y = xo.y + alpha*po.y;
            xn.z = xo.z + alpha*po.z;  xn.w = xo.w + alpha*po.w;
            ((float4*)xnew)[tid + k*256] = xn;
        }
    }
    __syncthreads();
}

// ---------------- persistent fused CG: prep + all NITER iterations, 1 dispatch ----------------
// 1024 blocks x 256 thr = exactly 4 blocks/CU x 256 CUs, co-resident by
// construction (launch_bounds caps VGPR at 128; LDS 17.4KB x 4 = 70KB).
// Replaces 3 kernel boundaries (~15-25us each, R3->R4 evidence) with 3
// in-kernel grid barriers. Each block re-reads the Dh rows it wrote
// (same-XCD L2 locality).
__launch_bounds__(256, 4)
__global__ void k_cgp(const float* __restrict__ D, unsigned short* __restrict__ Dh,
                      const float* __restrict__ inp, const float* __restrict__ L,
                      const int*  __restrict__ mask, const float* __restrict__ thP,
                      const float* __restrict__ S,
                      const float* __restrict__ l1p, const float* __restrict__ l2p,
                      const float* __restrict__ rhop,
                      float* __restrict__ wf, uint* __restrict__ ctr){
    __shared__ float psh[NN];
    __shared__ float red[8];
    __shared__ float cparts[256];
    int tid = threadIdx.x;
    int wave = tid >> 6, lane = tid & 63;
    int row = blockIdx.x * 4 + wave;
    int u = row & 63, h = row >> 6;
    float l1 = l1p[0], l2 = l2p[0], rho = rhop[0];

    float* Xb[2]  = { wf + OFF_X0, wf + OFF_X1 };
    float* Rb[2]  = { wf + OFF_R0, wf + OFF_R1 };
    float* Pb[2]  = { wf + OFF_P0, wf + OFF_P1 };
    float* Yb[2]  = { wf + OFF_Y0, wf + OFF_Y1 };
    float* pty[2] = { wf + OFF_PTY0, wf + OFF_PTY1 };

    // ======== phase 0: prep + fp32 D matvec + emit bf16 Dh ========
    {
        // S column-norm^2 partials (for dinv): wave w covers hh = 16w..16w+15
        float cp = 0.f;
        for(int hh = wave*16; hh < wave*16 + 16; ++hh){
            float sv = S[hh*64 + lane];
            cp += sv * sv;
        }
        cparts[wave*64 + lane] = cp;
        // StS row u (this wave's row), element 'lane'  (S is 16KB -> L1-hot)
        float stv = 0.f;
        for(int hh = 0; hh < 64; ++hh)
            stv += S[hh*64 + u] * S[hh*64 + lane];
        if(row < 64) wf[OFF_STS + row*64 + lane] = stv;   // canonical StS (blocks 0..15)
        __syncthreads();

        // build p0 into psh (redundant per block); canonical inits from blocks 0..15
        int c = tid & 63;
        float cs4 = cparts[c] + cparts[64+c] + cparts[128+c] + cparts[192+c];
        bool canon = (blockIdx.x < 16);
        for(int k = 0; k < 16; ++k){
            int t = tid + k*256;                    // t&63 == tid&63
            float q = (mask[t] != 0) ? 1.f : 0.f;
            float bi = rho * (L[t] - thP[t]) + q * inp[t];
            float dinv = 1.f / (q + rho + l2 * cs4);
            psh[t] = bi * dinv;
            if(canon && k == (int)blockIdx.x){
                wf[OFF_QRHO + t] = q + rho;
                wf[OFF_DINV + t] = dinv;
                wf[OFF_X0 + t]   = 0.f;
                wf[OFF_R0 + t]   = bi;
                wf[OFF_P0 + t]   = bi * dinv;
            }
        }
        __syncthreads();

        const float* Drow = D + (size_t)row * NN;
        unsigned short* Dhrow = Dh + (size_t)row * NN;
        float dacc = 0.f;
        for(int j = 0; j < 16; ++j){
            int c0 = j*256 + lane*4;
            float4 dv = *(const float4*)(Drow + c0);
            float4 pa = *(const float4*)(psh + c0);
            dacc += dv.x*pa.x + dv.y*pa.y + dv.z*pa.z + dv.w*pa.w;
            uint2 o;
            o.x = f2b(dv.x) | (f2b(dv.y) << 16);
            o.y = f2b(dv.z) | (f2b(dv.w) << 16);
            *(uint2*)(Dhrow + c0) = o;
        }
        float sacc = stv * psh[h*64 + lane];
        float val = l1 * dacc + l2 * sacc;
        for(int m = 32; m >= 1; m >>= 1) val += __shfl_xor(val, m, 64);
        if(lane == 0){
            float qr = ((mask[row] != 0) ? 1.f : 0.f) + rho;   // local (canonical QRHO races in-phase)
            float yi = val + qr * psh[row];
            Yb[0][row] = yi;
            red[wave] = yi * psh[row];
        }
        __syncthreads();
        if(tid == 0) pty[0][blockIdx.x] = red[0] + red[1] + red[2] + red[3];
    }

    // ======== phases 1..NITER-1: prologue + bf16 matvec ========
    const float* qrho = wf + OFF_QRHO;
    const float* StS  = wf + OFF_STS;
    for(int it = 1; it < NITER; ++it){
        gridbar(ctr + (it-1)*32);

        int ro = (it+1)&1, wr = it&1;
        cg_prologue(wf, Rb[ro], Pb[ro], Xb[ro], Yb[ro],
                    Rb[wr], Pb[wr], Xb[wr], pty[(it-1)&1], psh, red);

        const unsigned short* Drow = Dh + (size_t)row * NN;
        float dacc = 0.f;
        for(int j = 0; j < 8; ++j){
            int c0 = j*512 + lane*8;
            uint4 dv = *(const uint4*)(Drow + c0);
            float4 pa = *(const float4*)(psh + c0);
            float4 pb = *(const float4*)(psh + c0 + 4);
            dacc += lo2f(dv.x)*pa.x + hi2f(dv.x)*pa.y
                  + lo2f(dv.y)*pa.z + hi2f(dv.y)*pa.w
                  + lo2f(dv.z)*pb.x + hi2f(dv.z)*pb.y
                  + lo2f(dv.w)*pb.z + hi2f(dv.w)*pb.w;
        }
        float sacc = StS[u*64 + lane] * psh[h*64 + lane];
        float val = l1 * dacc + l2 * sacc;
        for(int m = 32; m >= 1; m >>= 1) val += __shfl_xor(val, m, 64);
        if(lane == 0){
            float yi = val + qrho[row] * psh[row];
            Yb[wr][row] = yi;
            red[wave] = yi * psh[row];
        }
        __syncthreads();
        if(tid == 0) pty[it&1][blockIdx.x] = red[0] + red[1] + red[2] + red[3];
    }
}

// ---------------- CG step fp32 fallback (do_pro selects prologue) ----------------
__launch_bounds__(256)
__global__ void k_step_f(const float* __restrict__ D,
                         const float* __restrict__ l1p, const float* __restrict__ l2p,
                         float* __restrict__ wf,
                         const float* __restrict__ rold, const float* __restrict__ pold,
                         const float* __restrict__ xold, const float* __restrict__ yold,
                         float* __restrict__ rnew, float* __restrict__ pnew,
                         float* __restrict__ xnew, float* __restrict__ ynew,
                         const float* __restrict__ pty_read, float* __restrict__ pty_write,
                         int do_pro){
    __shared__ float psh[NN];
    __shared__ float red[8];
    int tid = threadIdx.x;
    if(do_pro){
        cg_prologue(wf, rold, pold, xold, yold, rnew, pnew, xnew, pty_read, psh, red);
    } else {
        for(int k = 0; k < 4; ++k)
            ((float4*)psh)[tid + k*256] = ((const float4*)pold)[tid + k*256];
        __syncthreads();
    }
    float l1 = l1p[0], l2 = l2p[0];
    int wave = tid >> 6, lane = tid & 63;
    int row = blockIdx.x * 4 + wave;
    int h = row >> 6, u = row & 63;
    const float* qrho = wf + OFF_QRHO;
    const float* StS  = wf + OFF_STS;
    const float* Drow = D + (size_t)row * NN;
    float dacc = 0.f;
    for(int j = 0; j < 16; ++j){
        int c0 = j*256 + lane*4;
        float4 dv = *(const float4*)(Drow + c0);
        float4 pa = *(const float4*)(psh + c0);
        dacc += dv.x*pa.x + dv.y*pa.y + dv.z*pa.z + dv.w*pa.w;
    }
    float sacc = StS[u*64 + lane] * psh[h*64 + lane];
    float val = l1 * dacc + l2 * sacc;
    for(int m = 32; m >= 1; m >>= 1) val += __shfl_xor(val, m, 64);
    if(lane == 0){
        float yi = val + qrho[row] * psh[row];
        ynew[row] = yi;
        red[wave] = yi * psh[row];
    }
    __syncthreads();
    if(tid == 0) pty_write[blockIdx.x] = red[0] + red[1] + red[2] + red[3];
}

// ---------------- SVT: register-resident Brent-Luk Jacobi + final CG update fused ----------------
#define P_MA(par) (POOL + (par)*2176)
#define P_MB(par) (POOL + 4352 + (par)*2176)
#define P_XSH     (POOL + 8704)
#define P_TSH     (POOL)
#define P_WC      (POOL + 4352)
#define DOT4(u,v) ((u).x*(v).x + (u).y*(v).y + (u).z*(v).z + (u).w*(v).w)

__launch_bounds__(512)
__global__ void k_svt(const float* __restrict__ thP, const float* __restrict__ vp,
                      const float* __restrict__ netap,
                      float* __restrict__ wf,
                      const float* __restrict__ rlast, const float* __restrict__ plast,
                      const float* __restrict__ xlast,
                      const float* __restrict__ ptyp,
                      float* __restrict__ out){
    __shared__ float POOL[12800];
    __shared__ float s2[64], coef3[64];
    __shared__ float smax_sh;
    __shared__ float redv[16];
    int tid = threadIdx.x;
    float* Xsh = P_XSH;

    // fused final CG update: alpha_last = rz_last / pTy_last ; X = x + alpha*p + thP
    {
        const float* dinv = wf + OFF_DINV;
        float part = 0.f;
        #pragma unroll
        for(int k = 0; k < 2; ++k){
            float4 r4 = ((const float4*)rlast)[tid + k*512];
            float4 d4 = ((const float4*)dinv)[tid + k*512];
            part += r4.x*r4.x*d4.x + r4.y*r4.y*d4.y + r4.z*r4.z*d4.z + r4.w*r4.w*d4.w;
        }
        float pp = ptyp[tid] + ptyp[tid + 512];
        for(int m = 32; m >= 1; m >>= 1){
            part += __shfl_xor(part, m, 64);
            pp   += __shfl_xor(pp, m, 64);
        }
        if((tid & 63) == 0){ redv[tid >> 6] = part; redv[8 + (tid >> 6)] = pp; }
        __syncthreads();
        float rz = redv[0] + redv[1] + redv[2] + redv[3]
                 + redv[4] + redv[5] + redv[6] + redv[7];
        float ptys = redv[8] + redv[9] + redv[10] + redv[11]
                   + redv[12] + redv[13] + redv[14] + redv[15];
        float a = rz / ptys;
        #pragma unroll
        for(int k = 0; k < 2; ++k){
            float4 x4 = ((const float4*)xlast)[tid + k*512];
            float4 p4 = ((const float4*)plast)[tid + k*512];
            float4 t4 = ((const float4*)thP)[tid + k*512];
            float4 v;
            v.x = x4.x + a*p4.x + t4.x;  v.y = x4.y + a*p4.y + t4.y;
            v.z = x4.z + a*p4.z + t4.z;  v.w = x4.w + a*p4.w + t4.w;
            ((float4*)Xsh)[tid + k*512] = v;
        }
    }
    __syncthreads();

    int g  = tid >> 4;      // group 0..31 (one aligned 16-lane DPP row)
    int sl = tid & 15;      // sub-lane: rows sl*4 .. sl*4+3
    float4 A, B;
    {
        int ca = 2*g, cb = 2*g + 1, r0 = sl*4;
        A.x = Xsh[(r0+0)*64+ca]; A.y = Xsh[(r0+1)*64+ca];
        A.z = Xsh[(r0+2)*64+ca]; A.w = Xsh[(r0+3)*64+ca];
        B.x = Xsh[(r0+0)*64+cb]; B.y = Xsh[(r0+1)*64+cb];
        B.z = Xsh[(r0+2)*64+cb]; B.w = Xsh[(r0+3)*64+cb];
    }
    float aa = rsum16(DOT4(A,A));
    float bb = rsum16(DOT4(B,B));

    const int total = NSWEEP * 63;
    for(int gr = 0; gr < total; ++gr){
        float cc = rsum16(DOT4(A,B));
        float cs = 1.f, sn = 0.f, t = 0.f;
        if(fabsf(cc) > 1e-30f){
            float zeta = (bb - aa) * 0.5f * __builtin_amdgcn_rcpf(cc);
            t = copysignf(__builtin_amdgcn_rcpf(fabsf(zeta) +
                          __builtin_amdgcn_sqrtf(1.f + zeta*zeta)), zeta);
            cs = __builtin_amdgcn_rsqf(1.f + t*t);
            sn = t * cs;
        }
        float naN = aa - t*cc;      // rotated-A squared norm (Golub update)
        float nbN = bb + t*cc;      // rotated-B squared norm
        if(gr != total - 1){
            int par = gr & 1;
            float* MAp = P_MA(par);
            float* MBp = P_MB(par);
            // rotate & ship outgoing B first (overlap write latency with A rotation)
            float4 nb;
            nb.x = sn*A.x + cs*B.x; nb.y = sn*A.y + cs*B.y;
            nb.z = sn*A.z + cs*B.z; nb.w = sn*A.w + cs*B.w;
            float* cbB = (g == 0) ? (MAp + 1*MCS) : (MBp + (g-1)*MCS);
            *(float4*)(cbB + sl*4) = nb;
            if(sl == 0) cbB[64] = nbN;
            float4 na;
            na.x = cs*A.x - sn*B.x; na.y = cs*A.y - sn*B.y;
            na.z = cs*A.z - sn*B.z; na.w = cs*A.w - sn*B.w;
            if(g >= 1 && g <= 30){
                float* cbA = MAp + (g+1)*MCS;
                *(float4*)(cbA + sl*4) = na;
                if(sl == 0) cbA[64] = naN;
            }
            __syncthreads();
            float4 nA = na;  float nAa = naN;   // g==0 keeps rotated A
            float4 nB = na;  float nBb = naN;   // g==31: new B = rotated A
            if(g >= 1){
                const float* ra = MAp + g*MCS;
                nA = *(const float4*)(ra + sl*4);
                nAa = ra[64];
            }
            if(g <= 30){
                const float* rb = MBp + g*MCS;
                nB = *(const float4*)(rb + sl*4);
                nBb = rb[64];
            }
            A = nA; B = nB; aa = nAa; bb = nBb;
        } else {
            float4 na;
            na.x = cs*A.x - sn*B.x; na.y = cs*A.y - sn*B.y;
            na.z = cs*A.z - sn*B.z; na.w = cs*A.w - sn*B.w;
            float4 nbf;
            nbf.x = sn*A.x + cs*B.x; nbf.y = sn*A.y + cs*B.y;
            nbf.z = sn*A.z + cs*B.z; nbf.w = sn*A.w + cs*B.w;
            A = na; B = nbf;
        }
    }
    // final column norms (exact, drift-free) + store W to LDS
    {
        float fa = rsum16(DOT4(A,A));
        float fb = rsum16(DOT4(B,B));
        __syncthreads();   // mailbox reads done before Wc (aliases MB) written
        float* Wc = P_WC;
        *(float4*)(Wc + (2*g)*MCS + sl*4)   = A;
        *(float4*)(Wc + (2*g+1)*MCS + sl*4) = B;
        if(sl == 0){ s2[2*g] = fa; s2[2*g+1] = fb; }
    }
    __syncthreads();
    if(tid == 0){
        float sm = 0.f;
        for(int c = 0; c < 64; ++c) sm = fmaxf(sm, s2[c]);
        smax_sh = sqrtf(sm);
    }
    __syncthreads();
    if(tid < 64){
        float s = sqrtf(s2[tid]);
        float v = vp[0];
        float tau = 0.4f / (1.f + expf(-v));     // sigmoid(v)*COEF_GAMMA
        float thr = tau * smax_sh;
        coef3[tid] = (s > thr && s > 1e-20f) ? (s - thr) / (s*s*s) : 0.f;
    }
    __syncthreads();

    const float* Wc = P_WC;
    float* Tsh = P_TSH;
    // R1: T'[k][j] = coef3[k] * sum_r Wc[k][r] * Xsh[r][j]   (8 cols per thread)
    {
        int kk = tid >> 3;
        int j0 = (tid & 7) * 8;
        float acc[8];
        #pragma unroll
        for(int j = 0; j < 8; ++j) acc[j] = 0.f;
        for(int r = 0; r < 64; ++r){
            float wk = Wc[kk*MCS + r];
            const float* xr = Xsh + r*64 + j0;
            float4 x0 = *(const float4*)(xr);
            float4 x1 = *(const float4*)(xr + 4);
            acc[0]+=wk*x0.x; acc[1]+=wk*x0.y; acc[2]+=wk*x0.z; acc[3]+=wk*x0.w;
            acc[4]+=wk*x1.x; acc[5]+=wk*x1.y; acc[6]+=wk*x1.z; acc[7]+=wk*x1.w;
        }
        float c3 = coef3[kk];
        float* tr = Tsh + kk*64 + j0;
        float4 t0, t1;
        t0.x = c3*acc[0]; t0.y = c3*acc[1]; t0.z = c3*acc[2]; t0.w = c3*acc[3];
        t1.x = c3*acc[4]; t1.y = c3*acc[5]; t1.z = c3*acc[6]; t1.w = c3*acc[7];
        *(float4*)(tr)     = t0;
        *(float4*)(tr + 4) = t1;
    }
    __syncthreads();

    // R2: Ltmp[i][j] = sum_k Wc[k][i] * T'[k][j]; outputs   (8 cols per thread)
    {
        float neta = netap[0];
        int i  = tid >> 3;
        int j0 = (tid & 7) * 8;
        float acc[8];
        #pragma unroll
        for(int j = 0; j < 8; ++j) acc[j] = 0.f;
        for(int kk = 0; kk < 64; ++kk){
            float wik = Wc[kk*MCS + i];
            const float* tr = Tsh + kk*64 + j0;
            float4 t0 = *(const float4*)(tr);
            float4 t1 = *(const float4*)(tr + 4);
            acc[0]+=wik*t0.x; acc[1]+=wik*t0.y; acc[2]+=wik*t0.z; acc[3]+=wik*t0.w;
            acc[4]+=wik*t1.x; acc[5]+=wik*t1.y; acc[6]+=wik*t1.z; acc[7]+=wik*t1.w;
        }
        int n0 = i*64 + j0;
        #pragma unroll
        for(int c = 0; c < 2; ++c){
            float4 th = *(const float4*)(thP + n0 + 4*c);
            float4 lt, pt;
            lt.x = acc[4*c+0]; lt.y = acc[4*c+1]; lt.z = acc[4*c+2]; lt.w = acc[4*c+3];
            float4 xs = *(const float4*)(Xsh + n0 + 4*c);
            pt.x = th.x + neta * (xs.x - th.x - lt.x);
            pt.y = th.y + neta * (xs.y - th.y - lt.y);
            pt.z = th.z + neta * (xs.z - th.z - lt.z);
            pt.w = th.w + neta * (xs.w - th.w - lt.w);
            *(float4*)(out + n0 + 4*c)      = lt;
            *(float4*)(out + NN + n0 + 4*c) = pt;
        }
    }
}

extern "C" void kernel_launch(void* const* d_in, const int* in_sizes, int n_in,
                              void* d_out, int out_size, void* d_ws, size_t ws_size,
                              hipStream_t stream){
    const float* inp  = (const float*)d_in[0];
    const float* L    = (const float*)d_in[1];
    const int*   mask = (const int*)  d_in[2];
    const float* D    = (const float*)d_in[3];
    const float* thP  = (const float*)d_in[4];
    const float* vS   = (const float*)d_in[5];
    const float* neta = (const float*)d_in[6];
    const float* l1   = (const float*)d_in[7];
    const float* l2   = (const float*)d_in[8];
    const float* rho  = (const float*)d_in[9];
    const float* S    = (const float*)d_in[10];
    float* wf = (float*)d_ws;
    float* out = (float*)d_out;
    const bool use_bf16 = (ws_size >= WS_NEED_BF16);
    unsigned short* Dh = (unsigned short*)((char*)d_ws + DH_OFF_BYTES);

    float* Xb[2]  = { wf + OFF_X0, wf + OFF_X1 };
    float* Rb[2]  = { wf + OFF_R0, wf + OFF_R1 };
    float* Pb[2]  = { wf + OFF_P0, wf + OFF_P1 };
    float* Yb[2]  = { wf + OFF_Y0, wf + OFF_Y1 };
    float* pty[2] = { wf + OFF_PTY0, wf + OFF_PTY1 };
    uint*  ctr    = (uint*)(wf + OFF_CTR);

    if(use_bf16){
        hipMemsetAsync(ctr, 0, 3 * 32 * sizeof(uint), stream);   // barrier counters
        k_cgp<<<GRID_CG, 256, 0, stream>>>(D, Dh, inp, L, mask, thP, S,
                                           l1, l2, rho, wf, ctr);
    } else {
        k_prep<<<16, 256, 0, stream>>>(inp, L, mask, thP, S, l2, rho, wf);
        k_step_f<<<1024, 256, 0, stream>>>(D, l1, l2, wf,
            Rb[0], Pb[0], Xb[0], Yb[0], Rb[1], Pb[1], Xb[1], Yb[0],
            pty[0], pty[0], 0);
        for(int j = 1; j < NITER; ++j){
            int ro = (j+1)&1, wr = j&1;
            k_step_f<<<1024, 256, 0, stream>>>(D, l1, l2, wf,
                Rb[ro], Pb[ro], Xb[ro], Yb[ro],
                Rb[wr], Pb[wr], Xb[wr], Yb[wr],
                pty[(j-1)&1], pty[j&1], 1);
        }
    }
    // NITER=4 -> last write parity = (NITER-1)&1 = 1
    const int lp = (NITER-1)&1;
    k_svt<<<1, 512, 0, stream>>>(thP, vS, neta, wf, Rb[lp], Pb[lp], Xb[lp],
                                 pty[lp], out);
}

// Round 6
// 461.708 us; speedup vs baseline: 2.3126x; 2.3126x over previous
//
#include <hip/hip_runtime.h>
#include <hip/hip_bf16.h>

#define NN 4096
#define NITER 4
#define NSWEEP 5
#define MCS 68     // mailbox/Wc column stride (floats); [64] holds the column's squared norm

// workspace float layout
#define OFF_STS  64
#define OFF_QRHO (OFF_STS + NN)
#define OFF_DINV (OFF_QRHO + NN)
#define OFF_Y0   (OFF_DINV + NN)
#define OFF_Y1   (OFF_Y0 + NN)
#define OFF_X0   (OFF_Y1 + NN)
#define OFF_X1   (OFF_X0 + NN)
#define OFF_R0   (OFF_X1 + NN)
#define OFF_R1   (OFF_R0 + NN)
#define OFF_P0   (OFF_R1 + NN)
#define OFF_P1   (OFF_P0 + NN)
#define OFF_PTY0 (OFF_P1 + NN)
#define OFF_PTY1 (OFF_PTY0 + 1024)
// grid-barrier counters: 3 phases x 32-dword spacing, zeroed per replay
#define OFF_CTR  (OFF_PTY1 + 1024)
#define DH_OFF_BYTES 196608
#define WS_NEED_BF16 (DH_OFF_BYTES + (size_t)NN * NN * 2)
#define GRID_CG 1024

typedef unsigned int uint;
__device__ inline float lo2f(uint w){ return __uint_as_float(w << 16); }
__device__ inline float hi2f(uint w){ return __uint_as_float(w & 0xffff0000u); }
__device__ inline uint f2b(float f){
    uint u = __float_as_uint(f);
    return (u + 0x7FFFu + ((u >> 16) & 1u)) >> 16;   // RNE
}
__device__ inline float rsum16(float x){
    int a = __builtin_amdgcn_update_dpp(0, __float_as_int(x), 0xB1, 0xF, 0xF, true);
    float s = x + __int_as_float(a);
    int b = __builtin_amdgcn_update_dpp(0, __float_as_int(s), 0x4E, 0xF, 0xF, true);
    s = s + __int_as_float(b);
    int c = __builtin_amdgcn_update_dpp(0, __float_as_int(s), 0x141, 0xF, 0xF, true);  // row_half_mirror
    s = s + __int_as_float(c);
    int d = __builtin_amdgcn_update_dpp(0, __float_as_int(s), 0x140, 0xF, 0xF, true);  // row_mirror
    s = s + __int_as_float(d);
    return s;
}

__device__ inline float aload(const float* p){
    return __hip_atomic_load(p, __ATOMIC_RELAXED, __HIP_MEMORY_SCOPE_AGENT);
}
__device__ inline void astore(float* p, float v){
    __hip_atomic_store(p, v, __ATOMIC_RELAXED, __HIP_MEMORY_SCOPE_AGENT);
}

// ---- fence-free grid barrier: all cross-block data travels via agent-scope
// relaxed atomics (coherent-point, cache-bypassing), so NO __threadfence /
// L2 writeback/invalidate is needed (R5's 860us stall was exactly that storm).
// s_waitcnt vmcnt(0) per wave guarantees this wave's data atomics completed
// before the counter bump. Bounded spin: fails loud, never hangs.
__device__ inline void gridbar(uint* c){
    asm volatile("s_waitcnt vmcnt(0)" ::: "memory");
    __syncthreads();
    if(threadIdx.x == 0){
        __hip_atomic_fetch_add(c, 1u, __ATOMIC_RELAXED, __HIP_MEMORY_SCOPE_AGENT);
        long guard = 0;
        while(__hip_atomic_load(c, __ATOMIC_RELAXED, __HIP_MEMORY_SCOPE_AGENT) < (uint)GRID_CG){
            __builtin_amdgcn_s_sleep(8);
            if(++guard > 200000L) break;   // ~85ms cap: wrong answer, not a hang
        }
    }
    __syncthreads();
}

// ---------------- prep (FALLBACK PATH ONLY) ----------------
__global__ void k_prep(const float* __restrict__ inp, const float* __restrict__ L,
                       const int*  __restrict__ mask, const float* __restrict__ thP,
                       const float* __restrict__ S,
                       const float* __restrict__ l2p, const float* __restrict__ rhop,
                       float* __restrict__ wf){
    int t = blockIdx.x * 256 + threadIdx.x;
    int r = t >> 6, c = t & 63;
    float acc = 0.f, acc2 = 0.f;
    for(int h = 0; h < 64; ++h){
        float sr = S[h*64 + r];
        float sc = S[h*64 + c];
        acc  += sr * sc;
        acc2 += sc * sc;
    }
    wf[OFF_STS + t] = acc;
    float rho = rhop[0], l2 = l2p[0];
    float q = (mask[t] != 0) ? 1.f : 0.f;
    float bi = rho * (L[t] - thP[t]) + q * inp[t];
    float dinv = 1.f / (q + rho + l2 * acc2);
    wf[OFF_QRHO + t] = q + rho;
    wf[OFF_DINV + t] = dinv;
    wf[OFF_X0 + t]   = 0.f;
    wf[OFF_R0 + t]   = bi;
    wf[OFF_P0 + t]   = bi * dinv;
}

// ---------------- per-block redundant CG scalar update (fallback path) ----------------
__device__ inline void cg_prologue(float* __restrict__ wf,
                                   const float* __restrict__ rold, const float* __restrict__ pold,
                                   const float* __restrict__ xold, const float* __restrict__ yold,
                                   float* __restrict__ rnew, float* __restrict__ pnew,
                                   float* __restrict__ xnew,
                                   const float* __restrict__ pty_read,
                                   float* __restrict__ psh,
                                   float* __restrict__ red){
    int tid = threadIdx.x;
    const float* dinv = wf + OFF_DINV;
    float4 r4[4], d4[4];
    float part = 0.f;
    #pragma unroll
    for(int k = 0; k < 4; ++k){
        r4[k] = ((const float4*)rold)[tid + k*256];
        d4[k] = ((const float4*)dinv)[tid + k*256];
        part += r4[k].x*r4[k].x*d4[k].x + r4[k].y*r4[k].y*d4[k].y
              + r4[k].z*r4[k].z*d4[k].z + r4[k].w*r4[k].w*d4[k].w;
    }
    float pp = pty_read[tid] + pty_read[tid+256] + pty_read[tid+512] + pty_read[tid+768];
    for(int m = 32; m >= 1; m >>= 1){
        part += __shfl_xor(part, m, 64);
        pp   += __shfl_xor(pp, m, 64);
    }
    int wave = tid >> 6, lane = tid & 63;
    if(lane == 0){ red[wave] = part; red[4+wave] = pp; }
    __syncthreads();
    float rzold = red[0] + red[1] + red[2] + red[3];
    float ptys  = red[4] + red[5] + red[6] + red[7];
    float alpha = rzold / ptys;
    float4 rn[4], zn[4];
    float part2 = 0.f;
    #pragma unroll
    for(int k = 0; k < 4; ++k){
        float4 y4 = ((const float4*)yold)[tid + k*256];
        rn[k].x = r4[k].x - alpha*y4.x;  rn[k].y = r4[k].y - alpha*y4.y;
        rn[k].z = r4[k].z - alpha*y4.z;  rn[k].w = r4[k].w - alpha*y4.w;
        zn[k].x = rn[k].x*d4[k].x;  zn[k].y = rn[k].y*d4[k].y;
        zn[k].z = rn[k].z*d4[k].z;  zn[k].w = rn[k].w*d4[k].w;
        part2 += rn[k].x*zn[k].x + rn[k].y*zn[k].y + rn[k].z*zn[k].z + rn[k].w*zn[k].w;
    }
    for(int m = 32; m >= 1; m >>= 1) part2 += __shfl_xor(part2, m, 64);
    __syncthreads();
    if(lane == 0) red[wave] = part2;
    __syncthreads();
    float rznew = red[0] + red[1] + red[2] + red[3];
    float beta = rznew / rzold;
    bool b0 = (blockIdx.x == 0);
    #pragma unroll
    for(int k = 0; k < 4; ++k){
        float4 po = ((const float4*)pold)[tid + k*256];
        float4 pn;
        pn.x = zn[k].x + beta*po.x;  pn.y = zn[k].y + beta*po.y;
        pn.z = zn[k].z + beta*po.z;  pn.w = zn[k].w + beta*po.w;
        ((float4*)psh)[tid + k*256] = pn;
        if(b0){
            ((float4*)pnew)[tid + k*256] = pn;
            ((float4*)rnew)[tid + k*256] = rn[k];
            float4 xo = ((const float4*)xold)[tid + k*256];
            float4 xn;
            xn.x = xo.x + alpha*po.x;  xn.y = xo.y + alpha*po.y;
            xn.z = xo.z + alpha*po.z;  xn.w = xo.w + alpha*po.w;
            ((float4*)xnew)[tid + k*256] = xn;
        }
    }
    __syncthreads();
}

// ---------------- persistent fused CG v2: fence-free, block-local r/p/x ----------------
// Each block keeps FULL copies of r (regs), x (regs), dinv (regs), p (LDS) and
// recomputes alpha/beta redundantly (bitwise-identical across blocks). The only
// cross-block data per barrier is y (atomics) + pty partials (atomics). Dh is
// written and re-read by the SAME block (no coherence needed). Block 0 writes
// canonical r/p/x/dinv for k_svt; the kernel boundary flushes those.
__launch_bounds__(256, 4)
__global__ void k_cgp(const float* __restrict__ D, unsigned short* __restrict__ Dh,
                      const float* __restrict__ inp, const float* __restrict__ L,
                      const int*  __restrict__ mask, const float* __restrict__ thP,
                      const float* __restrict__ S,
                      const float* __restrict__ l1p, const float* __restrict__ l2p,
                      const float* __restrict__ rhop,
                      float* __restrict__ wf, uint* __restrict__ ctr){
    __shared__ float psh[NN];
    __shared__ float red[8];
    __shared__ float cparts[256];
    __shared__ float cols[64];
    int tid = threadIdx.x;
    int wave = tid >> 6, lane = tid & 63;
    int row = blockIdx.x * 4 + wave;
    int u = row & 63, h = row >> 6;
    float l1 = l1p[0], l2 = l2p[0], rho = rhop[0];
    bool b0 = (blockIdx.x == 0);

    float* Yb[2]  = { wf + OFF_Y0, wf + OFF_Y1 };
    float* pty[2] = { wf + OFF_PTY0, wf + OFF_PTY1 };

    float4 r4[4], x4[4], d4[4];   // block-local full CG state (element e = 4*tid + c + k*1024)

    // ---- phase 0: prep (local) ----
    {
        float cp = 0.f;
        for(int hh = wave*16; hh < wave*16 + 16; ++hh){
            float sv = S[hh*64 + lane];
            cp += sv * sv;
        }
        cparts[wave*64 + lane] = cp;
    }
    float stv = 0.f;   // StS[u][lane], kept in-register for all phases
    for(int hh = 0; hh < 64; ++hh)
        stv += S[hh*64 + u] * S[hh*64 + lane];
    __syncthreads();
    if(tid < 64) cols[tid] = cparts[tid] + cparts[64+tid] + cparts[128+tid] + cparts[192+tid];
    __syncthreads();

    #pragma unroll
    for(int k = 0; k < 4; ++k){
        int e0 = 4*tid + k*1024;
        float4 Lv = *(const float4*)(L + e0);
        float4 tv = *(const float4*)(thP + e0);
        float4 iv = *(const float4*)(inp + e0);
        int4   mv = *(const int4*)(mask + e0);
        float4 cv = *(const float4*)(cols + ((4*tid) & 63));
        float qx = mv.x ? 1.f : 0.f, qy = mv.y ? 1.f : 0.f;
        float qz = mv.z ? 1.f : 0.f, qw = mv.w ? 1.f : 0.f;
        float4 bi;
        bi.x = rho*(Lv.x - tv.x) + qx*iv.x;  bi.y = rho*(Lv.y - tv.y) + qy*iv.y;
        bi.z = rho*(Lv.z - tv.z) + qz*iv.z;  bi.w = rho*(Lv.w - tv.w) + qw*iv.w;
        d4[k].x = 1.f/(qx + rho + l2*cv.x);  d4[k].y = 1.f/(qy + rho + l2*cv.y);
        d4[k].z = 1.f/(qz + rho + l2*cv.z);  d4[k].w = 1.f/(qw + rho + l2*cv.w);
        r4[k] = bi;
        x4[k].x = 0.f; x4[k].y = 0.f; x4[k].z = 0.f; x4[k].w = 0.f;
        float4 p0;
        p0.x = bi.x*d4[k].x;  p0.y = bi.y*d4[k].y;
        p0.z = bi.z*d4[k].z;  p0.w = bi.w*d4[k].w;
        *(float4*)(psh + e0) = p0;
        if(b0) *(float4*)(wf + OFF_DINV + e0) = d4[k];   // canonical dinv for k_svt
    }
    __syncthreads();

    // ---- phase 0 matvec: fp32 D + emit bf16 Dh (own rows) ----
    {
        const float* Drow = D + (size_t)row * NN;
        unsigned short* Dhrow = Dh + (size_t)row * NN;
        float dacc = 0.f;
        for(int j = 0; j < 16; ++j){
            int c0 = j*256 + lane*4;
            float4 dv = *(const float4*)(Drow + c0);
            float4 pa = *(const float4*)(psh + c0);
            dacc += dv.x*pa.x + dv.y*pa.y + dv.z*pa.z + dv.w*pa.w;
            uint2 o;
            o.x = f2b(dv.x) | (f2b(dv.y) << 16);
            o.y = f2b(dv.z) | (f2b(dv.w) << 16);
            *(uint2*)(Dhrow + c0) = o;
        }
        float sacc = stv * psh[h*64 + lane];
        float val = l1 * dacc + l2 * sacc;
        for(int m = 32; m >= 1; m >>= 1) val += __shfl_xor(val, m, 64);
        if(lane == 0){
            float qr = ((mask[row] != 0) ? 1.f : 0.f) + rho;
            float yi = val + qr * psh[row];
            astore(&Yb[0][row], yi);
            red[wave] = yi * psh[row];
        }
        __syncthreads();
        if(tid == 0) astore(&pty[0][blockIdx.x], red[0] + red[1] + red[2] + red[3]);
    }

    // ---- iterations 1..NITER-1 ----
    for(int it = 1; it < NITER; ++it){
        gridbar(ctr + (it-1)*32);
        int ro = (it+1)&1, wr = it&1;

        // prologue on local state; y + pty via coherent atomics
        float part = 0.f;
        #pragma unroll
        for(int k = 0; k < 4; ++k){
            part += r4[k].x*r4[k].x*d4[k].x + r4[k].y*r4[k].y*d4[k].y
                  + r4[k].z*r4[k].z*d4[k].z + r4[k].w*r4[k].w*d4[k].w;
        }
        const float* pr = pty[(it-1)&1];
        float pp = aload(pr+tid) + aload(pr+tid+256) + aload(pr+tid+512) + aload(pr+tid+768);
        for(int m = 32; m >= 1; m >>= 1){
            part += __shfl_xor(part, m, 64);
            pp   += __shfl_xor(pp, m, 64);
        }
        if(lane == 0){ red[wave] = part; red[4+wave] = pp; }
        __syncthreads();
        float rzold = red[0] + red[1] + red[2] + red[3];
        float ptys  = red[4] + red[5] + red[6] + red[7];
        float alpha = rzold / ptys;
        const float* yo = Yb[ro];
        float4 zn4[4];
        float part2 = 0.f;
        #pragma unroll
        for(int k = 0; k < 4; ++k){
            int e0 = 4*tid + k*1024;
            float4 y4;
            y4.x = aload(yo + e0);     y4.y = aload(yo + e0 + 1);
            y4.z = aload(yo + e0 + 2); y4.w = aload(yo + e0 + 3);
            float4 rn;
            rn.x = r4[k].x - alpha*y4.x;  rn.y = r4[k].y - alpha*y4.y;
            rn.z = r4[k].z - alpha*y4.z;  rn.w = r4[k].w - alpha*y4.w;
            zn4[k].x = rn.x*d4[k].x;  zn4[k].y = rn.y*d4[k].y;
            zn4[k].z = rn.z*d4[k].z;  zn4[k].w = rn.w*d4[k].w;
            part2 += rn.x*zn4[k].x + rn.y*zn4[k].y + rn.z*zn4[k].z + rn.w*zn4[k].w;
            r4[k] = rn;
        }
        for(int m = 32; m >= 1; m >>= 1) part2 += __shfl_xor(part2, m, 64);
        __syncthreads();
        if(lane == 0) red[wave] = part2;
        __syncthreads();
        float beta = (red[0] + red[1] + red[2] + red[3]) / rzold;
        #pragma unroll
        for(int k = 0; k < 4; ++k){
            int e0 = 4*tid + k*1024;
            float4 po = *(const float4*)(psh + e0);
            x4[k].x += alpha*po.x;  x4[k].y += alpha*po.y;
            x4[k].z += alpha*po.z;  x4[k].w += alpha*po.w;
            float4 pn;
            pn.x = zn4[k].x + beta*po.x;  pn.y = zn4[k].y + beta*po.y;
            pn.z = zn4[k].z + beta*po.z;  pn.w = zn4[k].w + beta*po.w;
            *(float4*)(psh + e0) = pn;
        }
        __syncthreads();

        // bf16 matvec on own Dh rows
        const unsigned short* Drow = Dh + (size_t)row * NN;
        float dacc = 0.f;
        for(int j = 0; j < 8; ++j){
            int c0 = j*512 + lane*8;
            uint4 dv = *(const uint4*)(Drow + c0);
            float4 pa = *(const float4*)(psh + c0);
            float4 pb = *(const float4*)(psh + c0 + 4);
            dacc += lo2f(dv.x)*pa.x + hi2f(dv.x)*pa.y
                  + lo2f(dv.y)*pa.z + hi2f(dv.y)*pa.w
                  + lo2f(dv.z)*pb.x + hi2f(dv.z)*pb.y
                  + lo2f(dv.w)*pb.z + hi2f(dv.w)*pb.w;
        }
        float sacc = stv * psh[h*64 + lane];
        float val = l1 * dacc + l2 * sacc;
        for(int m = 32; m >= 1; m >>= 1) val += __shfl_xor(val, m, 64);
        if(lane == 0){
            float qr = ((mask[row] != 0) ? 1.f : 0.f) + rho;
            float yi = val + qr * psh[row];
            if(it < NITER-1) astore(&Yb[wr][row], yi);   // last iter's y unused
            red[wave] = yi * psh[row];
        }
        __syncthreads();
        if(tid == 0){
            float s = red[0] + red[1] + red[2] + red[3];
            if(it < NITER-1) astore(&pty[wr][blockIdx.x], s);
            else             pty[wr][blockIdx.x] = s;    // k_svt reads after boundary
        }
    }

    // canonical r/p/x for k_svt (lp = (NITER-1)&1 = 1); boundary flush makes visible
    if(b0){
        #pragma unroll
        for(int k = 0; k < 4; ++k){
            int e0 = 4*tid + k*1024;
            *(float4*)(wf + OFF_R1 + e0) = r4[k];
            *(float4*)(wf + OFF_X1 + e0) = x4[k];
            *(float4*)(wf + OFF_P1 + e0) = *(const float4*)(psh + e0);
        }
    }
}

// ---------------- CG step fp32 fallback (do_pro selects prologue) ----------------
__launch_bounds__(256)
__global__ void k_step_f(const float* __restrict__ D,
                         const float* __restrict__ l1p, const float* __restrict__ l2p,
                         float* __restrict__ wf,
                         const float* __restrict__ rold, const float* __restrict__ pold,
                         const float* __restrict__ xold, const float* __restrict__ yold,
                         float* __restrict__ rnew, float* __restrict__ pnew,
                         float* __restrict__ xnew, float* __restrict__ ynew,
                         const float* __restrict__ pty_read, float* __restrict__ pty_write,
                         int do_pro){
    __shared__ float psh[NN];
    __shared__ float red[8];
    int tid = threadIdx.x;
    if(do_pro){
        cg_prologue(wf, rold, pold, xold, yold, rnew, pnew, xnew, pty_read, psh, red);
    } else {
        for(int k = 0; k < 4; ++k)
            ((float4*)psh)[tid + k*256] = ((const float4*)pold)[tid + k*256];
        __syncthreads();
    }
    float l1 = l1p[0], l2 = l2p[0];
    int wave = tid >> 6, lane = tid & 63;
    int row = blockIdx.x * 4 + wave;
    int h = row >> 6, u = row & 63;
    const float* qrho = wf + OFF_QRHO;
    const float* StS  = wf + OFF_STS;
    const float* Drow = D + (size_t)row * NN;
    float dacc = 0.f;
    for(int j = 0; j < 16; ++j){
        int c0 = j*256 + lane*4;
        float4 dv = *(const float4*)(Drow + c0);
        float4 pa = *(const float4*)(psh + c0);
        dacc += dv.x*pa.x + dv.y*pa.y + dv.z*pa.z + dv.w*pa.w;
    }
    float sacc = StS[u*64 + lane] * psh[h*64 + lane];
    float val = l1 * dacc + l2 * sacc;
    for(int m = 32; m >= 1; m >>= 1) val += __shfl_xor(val, m, 64);
    if(lane == 0){
        float yi = val + qrho[row] * psh[row];
        ynew[row] = yi;
        red[wave] = yi * psh[row];
    }
    __syncthreads();
    if(tid == 0) pty_write[blockIdx.x] = red[0] + red[1] + red[2] + red[3];
}

// ---------------- SVT: register-resident Brent-Luk Jacobi + final CG update fused ----------------
#define P_MA(par) (POOL + (par)*2176)
#define P_MB(par) (POOL + 4352 + (par)*2176)
#define P_XSH     (POOL + 8704)
#define P_TSH     (POOL)
#define P_WC      (POOL + 4352)
#define DOT4(u,v) ((u).x*(v).x + (u).y*(v).y + (u).z*(v).z + (u).w*(v).w)

__launch_bounds__(512)
__global__ void k_svt(const float* __restrict__ thP, const float* __restrict__ vp,
                      const float* __restrict__ netap,
                      float* __restrict__ wf,
                      const float* __restrict__ rlast, const float* __restrict__ plast,
                      const float* __restrict__ xlast,
                      const float* __restrict__ ptyp,
                      float* __restrict__ out){
    __shared__ float POOL[12800];
    __shared__ float s2[64], coef3[64];
    __shared__ float smax_sh;
    __shared__ float redv[16];
    int tid = threadIdx.x;
    float* Xsh = P_XSH;

    {
        const float* dinv = wf + OFF_DINV;
        float part = 0.f;
        #pragma unroll
        for(int k = 0; k < 2; ++k){
            float4 r4 = ((const float4*)rlast)[tid + k*512];
            float4 d4 = ((const float4*)dinv)[tid + k*512];
            part += r4.x*r4.x*d4.x + r4.y*r4.y*d4.y + r4.z*r4.z*d4.z + r4.w*r4.w*d4.w;
        }
        float pp = ptyp[tid] + ptyp[tid + 512];
        for(int m = 32; m >= 1; m >>= 1){
            part += __shfl_xor(part, m, 64);
            pp   += __shfl_xor(pp, m, 64);
        }
        if((tid & 63) == 0){ redv[tid >> 6] = part; redv[8 + (tid >> 6)] = pp; }
        __syncthreads();
        float rz = redv[0] + redv[1] + redv[2] + redv[3]
                 + redv[4] + redv[5] + redv[6] + redv[7];
        float ptys = redv[8] + redv[9] + redv[10] + redv[11]
                   + redv[12] + redv[13] + redv[14] + redv[15];
        float a = rz / ptys;
        #pragma unroll
        for(int k = 0; k < 2; ++k){
            float4 x4 = ((const float4*)xlast)[tid + k*512];
            float4 p4 = ((const float4*)plast)[tid + k*512];
            float4 t4 = ((const float4*)thP)[tid + k*512];
            float4 v;
            v.x = x4.x + a*p4.x + t4.x;  v.y = x4.y + a*p4.y + t4.y;
            v.z = x4.z + a*p4.z + t4.z;  v.w = x4.w + a*p4.w + t4.w;
            ((float4*)Xsh)[tid + k*512] = v;
        }
    }
    __syncthreads();

    int g  = tid >> 4;
    int sl = tid & 15;
    float4 A, B;
    {
        int ca = 2*g, cb = 2*g + 1, r0 = sl*4;
        A.x = Xsh[(r0+0)*64+ca]; A.y = Xsh[(r0+1)*64+ca];
        A.z = Xsh[(r0+2)*64+ca]; A.w = Xsh[(r0+3)*64+ca];
        B.x = Xsh[(r0+0)*64+cb]; B.y = Xsh[(r0+1)*64+cb];
        B.z = Xsh[(r0+2)*64+cb]; B.w = Xsh[(r0+3)*64+cb];
    }
    float aa = rsum16(DOT4(A,A));
    float bb = rsum16(DOT4(B,B));

    const int total = NSWEEP * 63;
    for(int gr = 0; gr < total; ++gr){
        float cc = rsum16(DOT4(A,B));
        float cs = 1.f, sn = 0.f, t = 0.f;
        if(fabsf(cc) > 1e-30f){
            float zeta = (bb - aa) * 0.5f * __builtin_amdgcn_rcpf(cc);
            t = copysignf(__builtin_amdgcn_rcpf(fabsf(zeta) +
                          __builtin_amdgcn_sqrtf(1.f + zeta*zeta)), zeta);
            cs = __builtin_amdgcn_rsqf(1.f + t*t);
            sn = t * cs;
        }
        float naN = aa - t*cc;
        float nbN = bb + t*cc;
        if(gr != total - 1){
            int par = gr & 1;
            float* MAp = P_MA(par);
            float* MBp = P_MB(par);
            float4 nb;
            nb.x = sn*A.x + cs*B.x; nb.y = sn*A.y + cs*B.y;
            nb.z = sn*A.z + cs*B.z; nb.w = sn*A.w + cs*B.w;
            float* cbB = (g == 0) ? (MAp + 1*MCS) : (MBp + (g-1)*MCS);
            *(float4*)(cbB + sl*4) = nb;
            if(sl == 0) cbB[64] = nbN;
            float4 na;
            na.x = cs*A.x - sn*B.x; na.y = cs*A.y - sn*B.y;
            na.z = cs*A.z - sn*B.z; na.w = cs*A.w - sn*B.w;
            if(g >= 1 && g <= 30){
                float* cbA = MAp + (g+1)*MCS;
                *(float4*)(cbA + sl*4) = na;
                if(sl == 0) cbA[64] = naN;
            }
            __syncthreads();
            float4 nA = na;  float nAa = naN;
            float4 nB = na;  float nBb = naN;
            if(g >= 1){
                const float* ra = MAp + g*MCS;
                nA = *(const float4*)(ra + sl*4);
                nAa = ra[64];
            }
            if(g <= 30){
                const float* rb = MBp + g*MCS;
                nB = *(const float4*)(rb + sl*4);
                nBb = rb[64];
            }
            A = nA; B = nB; aa = nAa; bb = nBb;
        } else {
            float4 na;
            na.x = cs*A.x - sn*B.x; na.y = cs*A.y - sn*B.y;
            na.z = cs*A.z - sn*B.z; na.w = cs*A.w - sn*B.w;
            float4 nbf;
            nbf.x = sn*A.x + cs*B.x; nbf.y = sn*A.y + cs*B.y;
            nbf.z = sn*A.z + cs*B.z; nbf.w = sn*A.w + cs*B.w;
            A = na; B = nbf;
        }
    }
    {
        float fa = rsum16(DOT4(A,A));
        float fb = rsum16(DOT4(B,B));
        __syncthreads();
        float* Wc = P_WC;
        *(float4*)(Wc + (2*g)*MCS + sl*4)   = A;
        *(float4*)(Wc + (2*g+1)*MCS + sl*4) = B;
        if(sl == 0){ s2[2*g] = fa; s2[2*g+1] = fb; }
    }
    __syncthreads();
    if(tid == 0){
        float sm = 0.f;
        for(int c = 0; c < 64; ++c) sm = fmaxf(sm, s2[c]);
        smax_sh = sqrtf(sm);
    }
    __syncthreads();
    if(tid < 64){
        float s = sqrtf(s2[tid]);
        float v = vp[0];
        float tau = 0.4f / (1.f + expf(-v));
        float thr = tau * smax_sh;
        coef3[tid] = (s > thr && s > 1e-20f) ? (s - thr) / (s*s*s) : 0.f;
    }
    __syncthreads();

    const float* Wc = P_WC;
    float* Tsh = P_TSH;
    {
        int kk = tid >> 3;
        int j0 = (tid & 7) * 8;
        float acc[8];
        #pragma unroll
        for(int j = 0; j < 8; ++j) acc[j] = 0.f;
        for(int r = 0; r < 64; ++r){
            float wk = Wc[kk*MCS + r];
            const float* xr = Xsh + r*64 + j0;
            float4 x0 = *(const float4*)(xr);
            float4 x1 = *(const float4*)(xr + 4);
            acc[0]+=wk*x0.x; acc[1]+=wk*x0.y; acc[2]+=wk*x0.z; acc[3]+=wk*x0.w;
            acc[4]+=wk*x1.x; acc[5]+=wk*x1.y; acc[6]+=wk*x1.z; acc[7]+=wk*x1.w;
        }
        float c3 = coef3[kk];
        float* tr = Tsh + kk*64 + j0;
        float4 t0, t1;
        t0.x = c3*acc[0]; t0.y = c3*acc[1]; t0.z = c3*acc[2]; t0.w = c3*acc[3];
        t1.x = c3*acc[4]; t1.y = c3*acc[5]; t1.z = c3*acc[6]; t1.w = c3*acc[7];
        *(float4*)(tr)     = t0;
        *(float4*)(tr + 4) = t1;
    }
    __syncthreads();

    {
        float neta = netap[0];
        int i  = tid >> 3;
        int j0 = (tid & 7) * 8;
        float acc[8];
        #pragma unroll
        for(int j = 0; j < 8; ++j) acc[j] = 0.f;
        for(int kk = 0; kk < 64; ++kk){
            float wik = Wc[kk*MCS + i];
            const float* tr = Tsh + kk*64 + j0;
            float4 t0 = *(const float4*)(tr);
            float4 t1 = *(const float4*)(tr + 4);
            acc[0]+=wik*t0.x; acc[1]+=wik*t0.y; acc[2]+=wik*t0.z; acc[3]+=wik*t0.w;
            acc[4]+=wik*t1.x; acc[5]+=wik*t1.y; acc[6]+=wik*t1.z; acc[7]+=wik*t1.w;
        }
        int n0 = i*64 + j0;
        #pragma unroll
        for(int c = 0; c < 2; ++c){
            float4 th = *(const float4*)(thP + n0 + 4*c);
            float4 lt, pt;
            lt.x = acc[4*c+0]; lt.y = acc[4*c+1]; lt.z = acc[4*c+2]; lt.w = acc[4*c+3];
            float4 xs = *(const float4*)(Xsh + n0 + 4*c);
            pt.x = th.x + neta * (xs.x - th.x - lt.x);
            pt.y = th.y + neta * (xs.y - th.y - lt.y);
            pt.z = th.z + neta * (xs.z - th.z - lt.z);
            pt.w = th.w + neta * (xs.w - th.w - lt.w);
            *(float4*)(out + n0 + 4*c)      = lt;
            *(float4*)(out + NN + n0 + 4*c) = pt;
        }
    }
}

extern "C" void kernel_launch(void* const* d_in, const int* in_sizes, int n_in,
                              void* d_out, int out_size, void* d_ws, size_t ws_size,
                              hipStream_t stream){
    const float* inp  = (const float*)d_in[0];
    const float* L    = (const float*)d_in[1];
    const int*   mask = (const int*)  d_in[2];
    const float* D    = (const float*)d_in[3];
    const float* thP  = (const float*)d_in[4];
    const float* vS   = (const float*)d_in[5];
    const float* neta = (const float*)d_in[6];
    const float* l1   = (const float*)d_in[7];
    const float* l2   = (const float*)d_in[8];
    const float* rho  = (const float*)d_in[9];
    const float* S    = (const float*)d_in[10];
    float* wf = (float*)d_ws;
    float* out = (float*)d_out;
    const bool use_bf16 = (ws_size >= WS_NEED_BF16);
    unsigned short* Dh = (unsigned short*)((char*)d_ws + DH_OFF_BYTES);

    float* Xb[2]  = { wf + OFF_X0, wf + OFF_X1 };
    float* Rb[2]  = { wf + OFF_R0, wf + OFF_R1 };
    float* Pb[2]  = { wf + OFF_P0, wf + OFF_P1 };
    float* Yb[2]  = { wf + OFF_Y0, wf + OFF_Y1 };
    float* pty[2] = { wf + OFF_PTY0, wf + OFF_PTY1 };
    uint*  ctr    = (uint*)(wf + OFF_CTR);

    if(use_bf16){
        hipMemsetAsync(ctr, 0, 3 * 32 * sizeof(uint), stream);   // barrier counters
        k_cgp<<<GRID_CG, 256, 0, stream>>>(D, Dh, inp, L, mask, thP, S,
                                           l1, l2, rho, wf, ctr);
    } else {
        k_prep<<<16, 256, 0, stream>>>(inp, L, mask, thP, S, l2, rho, wf);
        k_step_f<<<1024, 256, 0, stream>>>(D, l1, l2, wf,
            Rb[0], Pb[0], Xb[0], Yb[0], Rb[1], Pb[1], Xb[1], Yb[0],
            pty[0], pty[0], 0);
        for(int j = 1; j < NITER; ++j){
            int ro = (j+1)&1, wr = j&1;
            k_step_f<<<1024, 256, 0, stream>>>(D, l1, l2, wf,
                Rb[ro], Pb[ro], Xb[ro], Yb[ro],
                Rb[wr], Pb[wr], Xb[wr], Yb[wr],
                pty[(j-1)&1], pty[j&1], 1);
        }
    }
    // NITER=4 -> last write parity = (NITER-1)&1 = 1
    const int lp = (NITER-1)&1;
    k_svt<<<1, 512, 0, stream>>>(thP, vS, neta, wf, Rb[lp], Pb[lp], Xb[lp],
                                 pty[lp], out);
}

// Round 7
// 280.011 us; speedup vs baseline: 3.8132x; 1.6489x over previous
//
#include <hip/hip_runtime.h>
#include <hip/hip_bf16.h>

#define NN 4096
#define NITER 4
#define NSWEEP 5
#define MCS 68     // mailbox/Wc column stride (floats); [64] holds the column's squared norm

// workspace float layout (double-buffered CG vectors INCLUDING y)
#define OFF_STS  64
#define OFF_QRHO (OFF_STS + NN)
#define OFF_DINV (OFF_QRHO + NN)
#define OFF_Y0   (OFF_DINV + NN)
#define OFF_Y1   (OFF_Y0 + NN)
#define OFF_X0   (OFF_Y1 + NN)
#define OFF_X1   (OFF_X0 + NN)
#define OFF_R0   (OFF_X1 + NN)
#define OFF_R1   (OFF_R0 + NN)
#define OFF_P0   (OFF_R1 + NN)
#define OFF_P1   (OFF_P0 + NN)
// per-block pTy partials, double-buffered by iteration parity
#define OFF_PTY0 (OFF_P1 + NN)
#define OFF_PTY1 (OFF_PTY0 + 1024)
#define DH_OFF_BYTES 196608
#define WS_NEED_BF16 (DH_OFF_BYTES + (size_t)NN * NN * 2)

typedef unsigned int uint;
__device__ inline float lo2f(uint w){ return __uint_as_float(w << 16); }
__device__ inline float hi2f(uint w){ return __uint_as_float(w & 0xffff0000u); }
__device__ inline uint f2b(float f){
    uint u = __float_as_uint(f);
    return (u + 0x7FFFu + ((u >> 16) & 1u)) >> 16;   // RNE
}
// 16-lane sum via DPP only (VALU latency, no DS pipe). Valid when the 16 lanes
// of a group are an aligned 16-lane DPP row (group g = lanes 16g..16g+15).
__device__ inline float rsum16(float x){
    int a = __builtin_amdgcn_update_dpp(0, __float_as_int(x), 0xB1, 0xF, 0xF, true);
    float s = x + __int_as_float(a);
    int b = __builtin_amdgcn_update_dpp(0, __float_as_int(s), 0x4E, 0xF, 0xF, true);
    s = s + __int_as_float(b);
    int c = __builtin_amdgcn_update_dpp(0, __float_as_int(s), 0x141, 0xF, 0xF, true);  // row_half_mirror
    s = s + __int_as_float(c);
    int d = __builtin_amdgcn_update_dpp(0, __float_as_int(s), 0x140, 0xF, 0xF, true);  // row_mirror
    s = s + __int_as_float(d);
    return s;
}

// ---------------- prep (FALLBACK PATH ONLY): StS + b + approx diag + CG init ----------------
__global__ void k_prep(const float* __restrict__ inp, const float* __restrict__ L,
                       const int*  __restrict__ mask, const float* __restrict__ thP,
                       const float* __restrict__ S,
                       const float* __restrict__ l2p, const float* __restrict__ rhop,
                       float* __restrict__ wf){
    int t = blockIdx.x * 256 + threadIdx.x;   // 4096 threads
    int r = t >> 6, c = t & 63;
    float acc = 0.f, acc2 = 0.f;
    for(int h = 0; h < 64; ++h){
        float sr = S[h*64 + r];
        float sc = S[h*64 + c];
        acc  += sr * sc;
        acc2 += sc * sc;
    }
    wf[OFF_STS + t] = acc;
    float rho = rhop[0], l2 = l2p[0];
    float q = (mask[t] != 0) ? 1.f : 0.f;
    float bi = rho * (L[t] - thP[t]) + q * inp[t];
    float dinv = 1.f / (q + rho + l2 * acc2);   // preconditioner only
    wf[OFF_QRHO + t] = q + rho;
    wf[OFF_DINV + t] = dinv;
    wf[OFF_X0 + t]   = 0.f;
    wf[OFF_R0 + t]   = bi;
    wf[OFF_P0 + t]   = bi * dinv;
}

// ---------------- per-block redundant CG scalar update (no fences needed) ----------------
// pTy of the previous iteration arrives as 1024 per-block partials; its sum is
// folded into the first shuffle-reduction tree (red[0..3]=rz, red[4..7]=pTy).
__device__ inline void cg_prologue(float* __restrict__ wf,
                                   const float* __restrict__ rold, const float* __restrict__ pold,
                                   const float* __restrict__ xold, const float* __restrict__ yold,
                                   float* __restrict__ rnew, float* __restrict__ pnew,
                                   float* __restrict__ xnew,
                                   const float* __restrict__ pty_read,
                                   float* __restrict__ psh,
                                   float* __restrict__ red){
    int tid = threadIdx.x;
    const float* dinv = wf + OFF_DINV;
    float4 r4[4], d4[4];
    float part = 0.f;
    #pragma unroll
    for(int k = 0; k < 4; ++k){
        r4[k] = ((const float4*)rold)[tid + k*256];
        d4[k] = ((const float4*)dinv)[tid + k*256];
        part += r4[k].x*r4[k].x*d4[k].x + r4[k].y*r4[k].y*d4[k].y
              + r4[k].z*r4[k].z*d4[k].z + r4[k].w*r4[k].w*d4[k].w;
    }
    float pp = pty_read[tid] + pty_read[tid+256] + pty_read[tid+512] + pty_read[tid+768];
    for(int m = 32; m >= 1; m >>= 1){
        part += __shfl_xor(part, m, 64);
        pp   += __shfl_xor(pp, m, 64);
    }
    int wave = tid >> 6, lane = tid & 63;
    if(lane == 0){ red[wave] = part; red[4+wave] = pp; }
    __syncthreads();
    float rzold = red[0] + red[1] + red[2] + red[3];
    float ptys  = red[4] + red[5] + red[6] + red[7];
    float alpha = rzold / ptys;
    float4 rn[4], zn[4];
    float part2 = 0.f;
    #pragma unroll
    for(int k = 0; k < 4; ++k){
        float4 y4 = ((const float4*)yold)[tid + k*256];
        rn[k].x = r4[k].x - alpha*y4.x;  rn[k].y = r4[k].y - alpha*y4.y;
        rn[k].z = r4[k].z - alpha*y4.z;  rn[k].w = r4[k].w - alpha*y4.w;
        zn[k].x = rn[k].x*d4[k].x;  zn[k].y = rn[k].y*d4[k].y;
        zn[k].z = rn[k].z*d4[k].z;  zn[k].w = rn[k].w*d4[k].w;
        part2 += rn[k].x*zn[k].x + rn[k].y*zn[k].y + rn[k].z*zn[k].z + rn[k].w*zn[k].w;
    }
    for(int m = 32; m >= 1; m >>= 1) part2 += __shfl_xor(part2, m, 64);
    __syncthreads();                      // all reads of red done
    if(lane == 0) red[wave] = part2;
    __syncthreads();
    float rznew = red[0] + red[1] + red[2] + red[3];
    float beta = rznew / rzold;
    bool b0 = (blockIdx.x == 0);
    #pragma unroll
    for(int k = 0; k < 4; ++k){
        float4 po = ((const float4*)pold)[tid + k*256];
        float4 pn;
        pn.x = zn[k].x + beta*po.x;  pn.y = zn[k].y + beta*po.y;
        pn.z = zn[k].z + beta*po.z;  pn.w = zn[k].w + beta*po.w;
        ((float4*)psh)[tid + k*256] = pn;
        if(b0){
            ((float4*)pnew)[tid + k*256] = pn;
            ((float4*)rnew)[tid + k*256] = rn[k];
            float4 xo = ((const float4*)xold)[tid + k*256];
            float4 xn;
            xn.x = xo.x + alpha*po.x;  xn.y = xo.y + alpha*po.y;
            xn.z = xo.z + alpha*po.z;  xn.w = xo.w + alpha*po.w;
            ((float4*)xnew)[tid + k*256] = xn;
        }
    }
    __syncthreads();
}

// ---------------- merged prep + CG step 0: fp32 D matvec + emit bf16 Dh ----------------
// Every block redundantly derives the prep quantities it needs (S col-norms,
// its 4 StS rows, full p0 in LDS); blocks 0..15 write the canonical wf arrays
// consumed by later kernels. Removes the separate k_prep dispatch.
__launch_bounds__(256)
__global__ void k_fc(const float* __restrict__ D, unsigned short* __restrict__ Dh,
                     const float* __restrict__ inp, const float* __restrict__ L,
                     const int*  __restrict__ mask, const float* __restrict__ thP,
                     const float* __restrict__ S,
                     const float* __restrict__ l1p, const float* __restrict__ l2p,
                     const float* __restrict__ rhop,
                     float* __restrict__ wf, float* __restrict__ pty_out){
    __shared__ float psh[NN];
    __shared__ float red[8];
    __shared__ float cparts[256];
    int tid = threadIdx.x;
    int wave = tid >> 6, lane = tid & 63;
    int row = blockIdx.x * 4 + wave;
    int u = row & 63, h = row >> 6;
    float l1 = l1p[0], l2 = l2p[0], rho = rhop[0];

    // S column-norm^2 partials (for dinv): wave w covers hh = 16w..16w+15
    {
        float cp = 0.f;
        for(int hh = wave*16; hh < wave*16 + 16; ++hh){
            float sv = S[hh*64 + lane];
            cp += sv * sv;
        }
        cparts[wave*64 + lane] = cp;
    }
    // StS row u (this wave's row), element 'lane'  (S is 16KB -> L1-hot)
    float stv = 0.f;
    for(int hh = 0; hh < 64; ++hh)
        stv += S[hh*64 + u] * S[hh*64 + lane];
    if(row < 64) wf[OFF_STS + row*64 + lane] = stv;   // canonical StS (blocks 0..15)
    __syncthreads();

    // build p0 into psh (redundant per block); canonical inits from blocks 0..15
    int c = tid & 63;
    float cs4 = cparts[c] + cparts[64+c] + cparts[128+c] + cparts[192+c];
    bool canon = (blockIdx.x < 16);
    for(int k = 0; k < 16; ++k){
        int t = tid + k*256;                    // t&63 == tid&63
        float q = (mask[t] != 0) ? 1.f : 0.f;
        float bi = rho * (L[t] - thP[t]) + q * inp[t];
        float dinv = 1.f / (q + rho + l2 * cs4);
        psh[t] = bi * dinv;
        if(canon && k == (int)blockIdx.x){
            wf[OFF_QRHO + t] = q + rho;
            wf[OFF_DINV + t] = dinv;
            wf[OFF_X0 + t]   = 0.f;
            wf[OFF_R0 + t]   = bi;
            wf[OFF_P0 + t]   = bi * dinv;
        }
    }
    __syncthreads();

    // fp32 matvec + emit bf16 Dh
    const float* Drow = D + (size_t)row * NN;
    unsigned short* Dhrow = Dh + (size_t)row * NN;
    float dacc = 0.f;
    for(int j = 0; j < 16; ++j){
        int c0 = j*256 + lane*4;
        float4 dv = *(const float4*)(Drow + c0);
        float4 pa = *(const float4*)(psh + c0);
        dacc += dv.x*pa.x + dv.y*pa.y + dv.z*pa.z + dv.w*pa.w;
        uint2 o;
        o.x = f2b(dv.x) | (f2b(dv.y) << 16);
        o.y = f2b(dv.z) | (f2b(dv.w) << 16);
        *(uint2*)(Dhrow + c0) = o;
    }
    float sacc = stv * psh[h*64 + lane];
    float val = l1 * dacc + l2 * sacc;
    for(int m = 32; m >= 1; m >>= 1) val += __shfl_xor(val, m, 64);
    if(lane == 0){
        float qr = ((mask[row] != 0) ? 1.f : 0.f) + rho;   // local (canonical QRHO may race in-kernel)
        float yi = val + qr * psh[row];
        (wf + OFF_Y0)[row] = yi;
        red[wave] = yi * psh[row];
    }
    __syncthreads();
    if(tid == 0) pty_out[blockIdx.x] = red[0] + red[1] + red[2] + red[3];
}

// ---------------- CG step j>=1: prologue + y = A p (bf16 D) + pTy partial ----------------
__launch_bounds__(256)
__global__ void k_step_h(const unsigned short* __restrict__ Dh,
                         const float* __restrict__ l1p, const float* __restrict__ l2p,
                         float* __restrict__ wf,
                         const float* __restrict__ rold, const float* __restrict__ pold,
                         const float* __restrict__ xold, const float* __restrict__ yold,
                         float* __restrict__ rnew, float* __restrict__ pnew,
                         float* __restrict__ xnew, float* __restrict__ ynew,
                         const float* __restrict__ pty_read, float* __restrict__ pty_write){
    __shared__ float psh[NN];
    __shared__ float red[8];
    int tid = threadIdx.x;
    cg_prologue(wf, rold, pold, xold, yold, rnew, pnew, xnew, pty_read, psh, red);

    float l1 = l1p[0], l2 = l2p[0];
    int wave = tid >> 6, lane = tid & 63;
    int row = blockIdx.x * 4 + wave;
    int h = row >> 6, u = row & 63;
    const float* qrho = wf + OFF_QRHO;
    const float* StS  = wf + OFF_STS;

    const unsigned short* Drow = Dh + (size_t)row * NN;
    float dacc = 0.f;
    for(int j = 0; j < 8; ++j){
        int c0 = j*512 + lane*8;
        uint4 dv = *(const uint4*)(Drow + c0);
        float4 pa = *(const float4*)(psh + c0);
        float4 pb = *(const float4*)(psh + c0 + 4);
        dacc += lo2f(dv.x)*pa.x + hi2f(dv.x)*pa.y
              + lo2f(dv.y)*pa.z + hi2f(dv.y)*pa.w
              + lo2f(dv.z)*pb.x + hi2f(dv.z)*pb.y
              + lo2f(dv.w)*pb.z + hi2f(dv.w)*pb.w;
    }
    float sacc = StS[u*64 + lane] * psh[h*64 + lane];
    float val = l1 * dacc + l2 * sacc;
    for(int m = 32; m >= 1; m >>= 1) val += __shfl_xor(val, m, 64);
    if(lane == 0){
        float yi = val + qrho[row] * psh[row];
        ynew[row] = yi;
        red[wave] = yi * psh[row];
    }
    __syncthreads();
    if(tid == 0) pty_write[blockIdx.x] = red[0] + red[1] + red[2] + red[3];
}

// ---------------- CG step fp32 fallback (do_pro selects prologue) ----------------
__launch_bounds__(256)
__global__ void k_step_f(const float* __restrict__ D,
                         const float* __restrict__ l1p, const float* __restrict__ l2p,
                         float* __restrict__ wf,
                         const float* __restrict__ rold, const float* __restrict__ pold,
                         const float* __restrict__ xold, const float* __restrict__ yold,
                         float* __restrict__ rnew, float* __restrict__ pnew,
                         float* __restrict__ xnew, float* __restrict__ ynew,
                         const float* __restrict__ pty_read, float* __restrict__ pty_write,
                         int do_pro){
    __shared__ float psh[NN];
    __shared__ float red[8];
    int tid = threadIdx.x;
    if(do_pro){
        cg_prologue(wf, rold, pold, xold, yold, rnew, pnew, xnew, pty_read, psh, red);
    } else {
        for(int k = 0; k < 4; ++k)
            ((float4*)psh)[tid + k*256] = ((const float4*)pold)[tid + k*256];
        __syncthreads();
    }
    float l1 = l1p[0], l2 = l2p[0];
    int wave = tid >> 6, lane = tid & 63;
    int row = blockIdx.x * 4 + wave;
    int h = row >> 6, u = row & 63;
    const float* qrho = wf + OFF_QRHO;
    const float* StS  = wf + OFF_STS;
    const float* Drow = D + (size_t)row * NN;
    float dacc = 0.f;
    for(int j = 0; j < 16; ++j){
        int c0 = j*256 + lane*4;
        float4 dv = *(const float4*)(Drow + c0);
        float4 pa = *(const float4*)(psh + c0);
        dacc += dv.x*pa.x + dv.y*pa.y + dv.z*pa.z + dv.w*pa.w;
    }
    float sacc = StS[u*64 + lane] * psh[h*64 + lane];
    float val = l1 * dacc + l2 * sacc;
    for(int m = 32; m >= 1; m >>= 1) val += __shfl_xor(val, m, 64);
    if(lane == 0){
        float yi = val + qrho[row] * psh[row];
        ynew[row] = yi;
        red[wave] = yi * psh[row];
    }
    __syncthreads();
    if(tid == 0) pty_write[blockIdx.x] = red[0] + red[1] + red[2] + red[3];
}

// ---------------- SVT: register-resident Brent-Luk Jacobi + final CG update fused ----------------
#define P_MA(par) (POOL + (par)*2176)
#define P_MB(par) (POOL + 4352 + (par)*2176)
#define P_XSH     (POOL + 8704)
#define P_TSH     (POOL)
#define P_WC      (POOL + 4352)
#define DOT4(u,v) ((u).x*(v).x + (u).y*(v).y + (u).z*(v).z + (u).w*(v).w)

__launch_bounds__(512)
__global__ void k_svt(const float* __restrict__ thP, const float* __restrict__ vp,
                      const float* __restrict__ netap,
                      float* __restrict__ wf,
                      const float* __restrict__ rlast, const float* __restrict__ plast,
                      const float* __restrict__ xlast,
                      const float* __restrict__ ptyp,
                      float* __restrict__ out){
    __shared__ float POOL[12800];
    __shared__ float s2[64], coef3[64];
    __shared__ float smax_sh;
    __shared__ float redv[16];
    int tid = threadIdx.x;
    float* Xsh = P_XSH;

    // fused final CG update: alpha_last = rz_last / pTy_last ; X = x + alpha*p + thP
    {
        const float* dinv = wf + OFF_DINV;
        float part = 0.f;
        #pragma unroll
        for(int k = 0; k < 2; ++k){
            float4 r4 = ((const float4*)rlast)[tid + k*512];
            float4 d4 = ((const float4*)dinv)[tid + k*512];
            part += r4.x*r4.x*d4.x + r4.y*r4.y*d4.y + r4.z*r4.z*d4.z + r4.w*r4.w*d4.w;
        }
        float pp = ptyp[tid] + ptyp[tid + 512];
        for(int m = 32; m >= 1; m >>= 1){
            part += __shfl_xor(part, m, 64);
            pp   += __shfl_xor(pp, m, 64);
        }
        if((tid & 63) == 0){ redv[tid >> 6] = part; redv[8 + (tid >> 6)] = pp; }
        __syncthreads();
        float rz = redv[0] + redv[1] + redv[2] + redv[3]
                 + redv[4] + redv[5] + redv[6] + redv[7];
        float ptys = redv[8] + redv[9] + redv[10] + redv[11]
                   + redv[12] + redv[13] + redv[14] + redv[15];
        float a = rz / ptys;
        #pragma unroll
        for(int k = 0; k < 2; ++k){
            float4 x4 = ((const float4*)xlast)[tid + k*512];
            float4 p4 = ((const float4*)plast)[tid + k*512];
            float4 t4 = ((const float4*)thP)[tid + k*512];
            float4 v;
            v.x = x4.x + a*p4.x + t4.x;  v.y = x4.y + a*p4.y + t4.y;
            v.z = x4.z + a*p4.z + t4.z;  v.w = x4.w + a*p4.w + t4.w;
            ((float4*)Xsh)[tid + k*512] = v;
        }
    }
    __syncthreads();

    int g  = tid >> 4;      // group 0..31 (one aligned 16-lane DPP row)
    int sl = tid & 15;      // sub-lane: rows sl*4 .. sl*4+3
    float4 A, B;
    {
        int ca = 2*g, cb = 2*g + 1, r0 = sl*4;
        A.x = Xsh[(r0+0)*64+ca]; A.y = Xsh[(r0+1)*64+ca];
        A.z = Xsh[(r0+2)*64+ca]; A.w = Xsh[(r0+3)*64+ca];
        B.x = Xsh[(r0+0)*64+cb]; B.y = Xsh[(r0+1)*64+cb];
        B.z = Xsh[(r0+2)*64+cb]; B.w = Xsh[(r0+3)*64+cb];
    }
    float aa = rsum16(DOT4(A,A));
    float bb = rsum16(DOT4(B,B));

    const int total = NSWEEP * 63;
    for(int gr = 0; gr < total; ++gr){
        float cc = rsum16(DOT4(A,B));
        // branch-free angle, 3 transcendentals (was 4 + exec-mask branch):
        // d=bb-aa; s=sqrt(d^2+4c^2); t = sgn(d)*2c/(|d|+s)  [== classic zeta form]
        float dd = bb - aa;
        float c2 = cc + cc;
        float s  = __builtin_amdgcn_sqrtf(__builtin_fmaf(dd, dd, c2*c2));
        float t0 = c2 * __builtin_amdgcn_rcpf(fabsf(dd) + s + 1e-30f);
        float t  = (dd < 0.f) ? -t0 : t0;
        float cs = __builtin_amdgcn_rsqf(__builtin_fmaf(t, t, 1.f));
        float sn = t * cs;
        float naN = aa - t*cc;      // rotated-A squared norm (Golub update)
        float nbN = bb + t*cc;      // rotated-B squared norm
        if(gr != total - 1){
            int par = gr & 1;
            float* MAp = P_MA(par);
            float* MBp = P_MB(par);
            // rotate & ship outgoing B first (overlap write latency with A rotation)
            float4 nb;
            nb.x = sn*A.x + cs*B.x; nb.y = sn*A.y + cs*B.y;
            nb.z = sn*A.z + cs*B.z; nb.w = sn*A.w + cs*B.w;
            float* cbB = (g == 0) ? (MAp + 1*MCS) : (MBp + (g-1)*MCS);
            *(float4*)(cbB + sl*4) = nb;
            if(sl == 0) cbB[64] = nbN;
            float4 na;
            na.x = cs*A.x - sn*B.x; na.y = cs*A.y - sn*B.y;
            na.z = cs*A.z - sn*B.z; na.w = cs*A.w - sn*B.w;
            if(g >= 1 && g <= 30){
                float* cbA = MAp + (g+1)*MCS;
                *(float4*)(cbA + sl*4) = na;
                if(sl == 0) cbA[64] = naN;
            }
            __syncthreads();
            float4 nA = na;  float nAa = naN;   // g==0 keeps rotated A
            float4 nB = na;  float nBb = naN;   // g==31: new B = rotated A
            if(g >= 1){
                const float* ra = MAp + g*MCS;
                nA = *(const float4*)(ra + sl*4);
                nAa = ra[64];
            }
            if(g <= 30){
                const float* rb = MBp + g*MCS;
                nB = *(const float4*)(rb + sl*4);
                nBb = rb[64];
            }
            A = nA; B = nB; aa = nAa; bb = nBb;
        } else {
            float4 na;
            na.x = cs*A.x - sn*B.x; na.y = cs*A.y - sn*B.y;
            na.z = cs*A.z - sn*B.z; na.w = cs*A.w - sn*B.w;
            float4 nbf;
            nbf.x = sn*A.x + cs*B.x; nbf.y = sn*A.y + cs*B.y;
            nbf.z = sn*A.z + cs*B.z; nbf.w = sn*A.w + cs*B.w;
            A = na; B = nbf;
        }
    }
    // final column norms (exact, drift-free) + store W to LDS
    {
        float fa = rsum16(DOT4(A,A));
        float fb = rsum16(DOT4(B,B));
        __syncthreads();   // mailbox reads done before Wc (aliases MB) written
        float* Wc = P_WC;
        *(float4*)(Wc + (2*g)*MCS + sl*4)   = A;
        *(float4*)(Wc + (2*g+1)*MCS + sl*4) = B;
        if(sl == 0){ s2[2*g] = fa; s2[2*g+1] = fb; }
    }
    __syncthreads();
    if(tid < 64){
        float v = s2[tid];
        for(int m = 32; m >= 1; m >>= 1) v = fmaxf(v, __shfl_xor(v, m, 64));
        if(tid == 0) smax_sh = sqrtf(v);
    }
    __syncthreads();
    if(tid < 64){
        float s = sqrtf(s2[tid]);
        float v = vp[0];
        float tau = 0.4f / (1.f + expf(-v));     // sigmoid(v)*COEF_GAMMA
        float thr = tau * smax_sh;
        coef3[tid] = (s > thr && s > 1e-20f) ? (s - thr) / (s*s*s) : 0.f;
    }
    __syncthreads();

    const float* Wc = P_WC;
    float* Tsh = P_TSH;
    // R1: T'[k][j] = coef3[k] * sum_r Wc[k][r] * Xsh[r][j]   (8 cols per thread)
    {
        int kk = tid >> 3;
        int j0 = (tid & 7) * 8;
        float acc[8];
        #pragma unroll
        for(int j = 0; j < 8; ++j) acc[j] = 0.f;
        for(int r = 0; r < 64; ++r){
            float wk = Wc[kk*MCS + r];
            const float* xr = Xsh + r*64 + j0;
            float4 x0 = *(const float4*)(xr);
            float4 x1 = *(const float4*)(xr + 4);
            acc[0]+=wk*x0.x; acc[1]+=wk*x0.y; acc[2]+=wk*x0.z; acc[3]+=wk*x0.w;
            acc[4]+=wk*x1.x; acc[5]+=wk*x1.y; acc[6]+=wk*x1.z; acc[7]+=wk*x1.w;
        }
        float c3 = coef3[kk];
        float* tr = Tsh + kk*64 + j0;
        float4 t0, t1;
        t0.x = c3*acc[0]; t0.y = c3*acc[1]; t0.z = c3*acc[2]; t0.w = c3*acc[3];
        t1.x = c3*acc[4]; t1.y = c3*acc[5]; t1.z = c3*acc[6]; t1.w = c3*acc[7];
        *(float4*)(tr)     = t0;
        *(float4*)(tr + 4) = t1;
    }
    __syncthreads();

    // R2: Ltmp[i][j] = sum_k Wc[k][i] * T'[k][j]; outputs   (8 cols per thread)
    {
        float neta = netap[0];
        int i  = tid >> 3;
        int j0 = (tid & 7) * 8;
        float acc[8];
        #pragma unroll
        for(int j = 0; j < 8; ++j) acc[j] = 0.f;
        for(int kk = 0; kk < 64; ++kk){
            float wik = Wc[kk*MCS + i];
            const float* tr = Tsh + kk*64 + j0;
            float4 t0 = *(const float4*)(tr);
            float4 t1 = *(const float4*)(tr + 4);
            acc[0]+=wik*t0.x; acc[1]+=wik*t0.y; acc[2]+=wik*t0.z; acc[3]+=wik*t0.w;
            acc[4]+=wik*t1.x; acc[5]+=wik*t1.y; acc[6]+=wik*t1.z; acc[7]+=wik*t1.w;
        }
        int n0 = i*64 + j0;
        #pragma unroll
        for(int c = 0; c < 2; ++c){
            float4 th = *(const float4*)(thP + n0 + 4*c);
            float4 lt, pt;
            lt.x = acc[4*c+0]; lt.y = acc[4*c+1]; lt.z = acc[4*c+2]; lt.w = acc[4*c+3];
            float4 xs = *(const float4*)(Xsh + n0 + 4*c);
            pt.x = th.x + neta * (xs.x - th.x - lt.x);
            pt.y = th.y + neta * (xs.y - th.y - lt.y);
            pt.z = th.z + neta * (xs.z - th.z - lt.z);
            pt.w = th.w + neta * (xs.w - th.w - lt.w);
            *(float4*)(out + n0 + 4*c)      = lt;
            *(float4*)(out + NN + n0 + 4*c) = pt;
        }
    }
}

extern "C" void kernel_launch(void* const* d_in, const int* in_sizes, int n_in,
                              void* d_out, int out_size, void* d_ws, size_t ws_size,
                              hipStream_t stream){
    const float* inp  = (const float*)d_in[0];
    const float* L    = (const float*)d_in[1];
    const int*   mask = (const int*)  d_in[2];
    const float* D    = (const float*)d_in[3];
    const float* thP  = (const float*)d_in[4];
    const float* vS   = (const float*)d_in[5];
    const float* neta = (const float*)d_in[6];
    const float* l1   = (const float*)d_in[7];
    const float* l2   = (const float*)d_in[8];
    const float* rho  = (const float*)d_in[9];
    const float* S    = (const float*)d_in[10];
    float* wf = (float*)d_ws;
    float* out = (float*)d_out;
    const bool use_bf16 = (ws_size >= WS_NEED_BF16);
    unsigned short* Dh = (unsigned short*)((char*)d_ws + DH_OFF_BYTES);

    float* Xb[2]  = { wf + OFF_X0, wf + OFF_X1 };
    float* Rb[2]  = { wf + OFF_R0, wf + OFF_R1 };
    float* Pb[2]  = { wf + OFF_P0, wf + OFF_P1 };
    float* Yb[2]  = { wf + OFF_Y0, wf + OFF_Y1 };
    float* pty[2] = { wf + OFF_PTY0, wf + OFF_PTY1 };

    if(use_bf16){
        // merged prep + iteration 0 (writes pty[0])
        k_fc<<<1024, 256, 0, stream>>>(D, Dh, inp, L, mask, thP, S,
                                       l1, l2, rho, wf, pty[0]);
        for(int j = 1; j < NITER; ++j){
            int ro = (j+1)&1, wr = j&1;
            k_step_h<<<1024, 256, 0, stream>>>(Dh, l1, l2, wf,
                Rb[ro], Pb[ro], Xb[ro], Yb[ro],
                Rb[wr], Pb[wr], Xb[wr], Yb[wr],
                pty[(j-1)&1], pty[j&1]);
        }
    } else {
        k_prep<<<16, 256, 0, stream>>>(inp, L, mask, thP, S, l2, rho, wf);
        k_step_f<<<1024, 256, 0, stream>>>(D, l1, l2, wf,
            Rb[0], Pb[0], Xb[0], Yb[0], Rb[1], Pb[1], Xb[1], Yb[0],
            pty[0], pty[0], 0);
        for(int j = 1; j < NITER; ++j){
            int ro = (j+1)&1, wr = j&1;
            k_step_f<<<1024, 256, 0, stream>>>(D, l1, l2, wf,
                Rb[ro], Pb[ro], Xb[ro], Yb[ro],
                Rb[wr], Pb[wr], Xb[wr], Yb[wr],
                pty[(j-1)&1], pty[j&1], 1);
        }
    }
    // NITER=4 -> last write parity = (NITER-1)&1 = 1
    const int lp = (NITER-1)&1;
    k_svt<<<1, 512, 0, stream>>>(thP, vS, neta, wf, Rb[lp], Pb[lp], Xb[lp],
                                 pty[lp], out);
}